// Round 1
// baseline (10261.139 us; speedup 1.0000x reference)
//
#include <hip/hip_runtime.h>

// LSTM T=256, N=128, D=H=1024, L=2.  Persistent cooperative kernel:
// 256 WGs x 512 thr (1 WG/CU).  WG (layer l, slice s) owns hidden units
// [8s, 8s+8) of layer l => 32 gate columns, weights pinned in LDS (131.6KB).
// Iteration tau: layer0 computes step tau, layer1 computes step tau-1
// (pipelined) -> ONE grid barrier per iteration, 257 total.
// fp16 MFMA 16x16x32, fp32 accum, c-state fp32.

typedef _Float16 f16;
typedef f16  v8f16 __attribute__((ext_vector_type(8)));
typedef float v4f32 __attribute__((ext_vector_type(4)));

#define TSTEPS 256

// ws layout (bytes)
#define OFF_W    0u
#define SZ_W     (2u*4096u*2048u*2u)   /* 33554432 fp16 weights [l][col][k] */
#define OFF_B    (OFF_W + SZ_W)
#define SZ_B     (2u*4096u*4u)          /* fused bias fp32 */
#define OFF_H0   (OFF_B + SZ_B)
#define SZ_H     (2u*128u*1024u*2u)     /* h double-buffer fp16 per layer */
#define OFF_H1   (OFF_H0 + SZ_H)
#define OFF_C    (OFF_H1 + SZ_H)
#define SZ_C     (2u*128u*1024u*4u)     /* c fp32 */
#define OFF_BAR  (OFF_C + SZ_C)         /* barrier: 512 uints */

__global__ void lstm_init(const float* __restrict__ h0, const float* __restrict__ c0,
                          const float* __restrict__ Wih, const float* __restrict__ Whh,
                          const float* __restrict__ bih, const float* __restrict__ bhh,
                          f16* __restrict__ wsW, float* __restrict__ wsB,
                          f16* __restrict__ hb0, f16* __restrict__ hb1,
                          float* __restrict__ wsC, unsigned* __restrict__ bar)
{
    size_t tid  = (size_t)blockIdx.x * blockDim.x + threadIdx.x;
    size_t nthr = (size_t)gridDim.x * blockDim.x;
    // weights: [l][col][k], k<1024 -> W_ih, k>=1024 -> W_hh  (16777216 elems)
    for (size_t i = tid; i < 16777216u; i += nthr) {
        unsigned l = (unsigned)(i >> 23), rem = (unsigned)(i & 8388607u);
        unsigned col = rem >> 11, k = rem & 2047u;
        float v = (k < 1024u) ? Wih[(size_t)l*4194304u + (size_t)col*1024u + k]
                              : Whh[(size_t)l*4194304u + (size_t)col*1024u + (k-1024u)];
        wsW[i] = (f16)v;
    }
    for (size_t i = tid; i < 8192u; i += nthr) wsB[i] = bih[i] + bhh[i];
    for (size_t i = tid; i < 131072u; i += nthr) {
        hb0[i]            = (f16)h0[i];             // layer0 h -> parity-0 buffer
        hb1[131072u + i]  = (f16)h0[131072u + i];   // layer1 h -> parity-1 buffer
    }
    for (size_t i = tid; i < 262144u; i += nthr) wsC[i] = c0[i];
    for (size_t i = tid; i < 512u;    i += nthr) bar[i] = 0u;
}

__device__ __forceinline__ float sigmoid_fast(float v) { return 1.0f / (1.0f + __expf(-v)); }
__device__ __forceinline__ float tanh_fast(float v)    { return 1.0f - 2.0f / (__expf(2.0f*v) + 1.0f); }

__device__ __forceinline__ v8f16 cvt8(v4f32 lo, v4f32 hi) {
    v8f16 r;
    r[0]=(f16)lo[0]; r[1]=(f16)lo[1]; r[2]=(f16)lo[2]; r[3]=(f16)lo[3];
    r[4]=(f16)hi[0]; r[5]=(f16)hi[1]; r[6]=(f16)hi[2]; r[7]=(f16)hi[3];
    return r;
}

// hierarchical grid barrier: 16 groups of 16 WGs, then root; all spin on gen.
__device__ __forceinline__ void grid_barrier_fn(unsigned* bar, int wgid, unsigned target) {
    __syncthreads();
    if (threadIdx.x == 0) {
        __builtin_amdgcn_fence(__ATOMIC_RELEASE, "agent");   // flush h/c stores to LLC
        unsigned* grp  = bar + ((wgid >> 4) << 4);           // 64B-spaced counters
        unsigned* root = bar + 384;
        unsigned* gen  = bar + 448;
        unsigned a = __hip_atomic_fetch_add(grp, 1u, __ATOMIC_ACQ_REL, __HIP_MEMORY_SCOPE_AGENT);
        if (a == 15u) {
            __hip_atomic_store(grp, 0u, __ATOMIC_RELAXED, __HIP_MEMORY_SCOPE_AGENT);
            unsigned r = __hip_atomic_fetch_add(root, 1u, __ATOMIC_ACQ_REL, __HIP_MEMORY_SCOPE_AGENT);
            if (r == 15u) {
                __hip_atomic_store(root, 0u, __ATOMIC_RELAXED, __HIP_MEMORY_SCOPE_AGENT);
                __hip_atomic_store(gen, target, __ATOMIC_RELEASE, __HIP_MEMORY_SCOPE_AGENT);
            }
        }
        while (__hip_atomic_load(gen, __ATOMIC_RELAXED, __HIP_MEMORY_SCOPE_AGENT) < target) {
            __builtin_amdgcn_s_sleep(4);
        }
        __builtin_amdgcn_fence(__ATOMIC_ACQUIRE, "agent");   // invalidate L1/L2 for fresh h
    }
    __syncthreads();
}

__global__ void __launch_bounds__(512)
lstm_main(const float* __restrict__ x, const f16* __restrict__ wsW,
          const float* __restrict__ wsB, f16* __restrict__ hb0, f16* __restrict__ hb1,
          float* __restrict__ wsC, float* __restrict__ out, unsigned* __restrict__ bar)
{
    __shared__ f16   wlds[32][2056];   // 32 gate cols x K=2048 (+8 pad), 131584 B
    __shared__ float glds[128][33];    // gate scratch [row][cc], 16896 B

    const int tid   = threadIdx.x;
    const int wgid  = blockIdx.x;
    const int layer = wgid >> 7;       // 0 or 1
    const int s     = wgid & 127;      // hidden slice: units [8s, 8s+8)
    const int lane  = tid & 63;
    const int wave  = tid >> 6;
    const int quad  = lane >> 4;
    const int l15   = lane & 15;
    const int rb    = wave & 3;        // row block: rows [32rb, 32rb+32)
    const int ks    = wave >> 2;       // k split: [1024ks, 1024ks+1024)

    // ---- stage weight slice into LDS (once) ----
    for (int idx = tid; idx < 8192; idx += 512) {
        int cc = idx >> 8;                        // 0..31 local col
        int k8 = (idx & 255) << 3;                // k offset, 8 halves
        int col = ((cc >> 3) << 10) + (s << 3) + (cc & 7);  // gate*1024 + 8s + u
        *(v8f16*)(&wlds[cc][k8]) =
            *(const v8f16*)(wsW + (((size_t)(layer*4096 + col)) << 11) + k8);
    }

    // ---- per-thread cell-update constants ----
    const int u  = tid & 7;
    const int jg = (s << 3) + u;                  // global hidden unit
    const float bi = wsB[layer*4096 +        jg];
    const float bf = wsB[layer*4096 + 1024 + jg];
    const float bg = wsB[layer*4096 + 2048 + jg];
    const float bo = wsB[layer*4096 + 3072 + jg];
    const int n1 = tid >> 3;                      // rows n1 and n1+64

    __syncthreads();

    const int kq   = quad << 3;
    const int row0 = (rb << 5) + l15;

    for (int tau = 0; tau <= TSTEPS; ++tau) {
        const int rbuf = tau & 1, wbuf = rbuf ^ 1;
        const bool active = layer ? (tau >= 1) : (tau < TSTEPS);
        if (active) {
            const int t = tau - layer;
            v4f32 acc[2][2] = {};   // [m-tile][n-tile]

            if (ks == 0 && layer == 0) {
                // input part of layer0: x[t] fp32 -> fp16 on the fly
                const float* p0 = x + (((size_t)t) << 17) + ((size_t)row0 << 10) + kq;
                const float* p1 = p0 + (16 << 10);
                #pragma unroll 4
                for (int k = 0; k < 1024; k += 32) {
                    v4f32 w0 = *(const v4f32*)(p0 + k), w1 = *(const v4f32*)(p0 + k + 4);
                    v4f32 y0 = *(const v4f32*)(p1 + k), y1 = *(const v4f32*)(p1 + k + 4);
                    v8f16 a0 = cvt8(w0, w1);
                    v8f16 a1 = cvt8(y0, y1);
                    v8f16 b0 = *(const v8f16*)(&wlds[l15     ][k + kq]);
                    v8f16 b1 = *(const v8f16*)(&wlds[16 + l15][k + kq]);
                    acc[0][0] = __builtin_amdgcn_mfma_f32_16x16x32_f16(a0, b0, acc[0][0], 0, 0, 0);
                    acc[0][1] = __builtin_amdgcn_mfma_f32_16x16x32_f16(a0, b1, acc[0][1], 0, 0, 0);
                    acc[1][0] = __builtin_amdgcn_mfma_f32_16x16x32_f16(a1, b0, acc[1][0], 0, 0, 0);
                    acc[1][1] = __builtin_amdgcn_mfma_f32_16x16x32_f16(a1, b1, acc[1][1], 0, 0, 0);
                }
            } else {
                // fp16 A source: layer1 input (ks==0) or recurrent h (ks==1)
                const f16* base = (ks == 0) ? (hb0 + rbuf * 131072)
                                            : ((layer ? hb1 : hb0) + rbuf * 131072);
                const int kofs = ks << 10;
                const f16* p0 = base + (row0 << 10) + kq;
                const f16* p1 = p0 + (16 << 10);
                #pragma unroll 8
                for (int k = 0; k < 1024; k += 32) {
                    v8f16 a0 = *(const v8f16*)(p0 + k);
                    v8f16 a1 = *(const v8f16*)(p1 + k);
                    v8f16 b0 = *(const v8f16*)(&wlds[l15     ][kofs + k + kq]);
                    v8f16 b1 = *(const v8f16*)(&wlds[16 + l15][kofs + k + kq]);
                    acc[0][0] = __builtin_amdgcn_mfma_f32_16x16x32_f16(a0, b0, acc[0][0], 0, 0, 0);
                    acc[0][1] = __builtin_amdgcn_mfma_f32_16x16x32_f16(a0, b1, acc[0][1], 0, 0, 0);
                    acc[1][0] = __builtin_amdgcn_mfma_f32_16x16x32_f16(a1, b0, acc[1][0], 0, 0, 0);
                    acc[1][1] = __builtin_amdgcn_mfma_f32_16x16x32_f16(a1, b1, acc[1][1], 0, 0, 0);
                }
            }

            // ---- reduce the 2 K-splits through LDS (C layout: row=quad*4+r, col=l15) ----
            if (ks == 0) {
                #pragma unroll
                for (int mt = 0; mt < 2; ++mt) {
                    int rrow = (rb << 5) + (mt << 4) + (quad << 2);
                    #pragma unroll
                    for (int r = 0; r < 4; ++r) {
                        glds[rrow + r][l15     ] = acc[mt][0][r];
                        glds[rrow + r][16 + l15] = acc[mt][1][r];
                    }
                }
            }
            __syncthreads();
            if (ks == 1) {
                #pragma unroll
                for (int mt = 0; mt < 2; ++mt) {
                    int rrow = (rb << 5) + (mt << 4) + (quad << 2);
                    #pragma unroll
                    for (int r = 0; r < 4; ++r) {
                        glds[rrow + r][l15     ] += acc[mt][0][r];
                        glds[rrow + r][16 + l15] += acc[mt][1][r];
                    }
                }
            }
            __syncthreads();

            // ---- cell update: 2 (row, unit) pairs per thread ----
            #pragma unroll
            for (int pp = 0; pp < 2; ++pp) {
                int n = n1 + (pp << 6);
                float gi = glds[n][u]      + bi;
                float gf = glds[n][8 + u]  + bf;
                float gg = glds[n][16 + u] + bg;
                float go = glds[n][24 + u] + bo;
                float si = sigmoid_fast(gi), sf = sigmoid_fast(gf), so = sigmoid_fast(go);
                float tg = tanh_fast(gg);
                float* cp = wsC + (layer << 17) + (n << 10) + jg;
                float cn = sf * (*cp) + si * tg;
                *cp = cn;
                float hv = so * tanh_fast(cn);
                if (layer == 1 && t == TSTEPS - 1) {
                    out[(n << 10) + jg] = hv;                   // final output, fp32
                } else {
                    f16* hw = (layer ? hb1 : hb0) + wbuf * 131072;
                    hw[(n << 10) + jg] = (f16)hv;
                }
            }
        }
        grid_barrier_fn(bar, wgid, (unsigned)(tau + 1));
    }
}

extern "C" void kernel_launch(void* const* d_in, const int* in_sizes, int n_in,
                              void* d_out, int out_size, void* d_ws, size_t ws_size,
                              hipStream_t stream) {
    const float* x   = (const float*)d_in[0];
    const float* h0  = (const float*)d_in[1];
    const float* c0  = (const float*)d_in[2];
    const float* Wih = (const float*)d_in[3];
    const float* Whh = (const float*)d_in[4];
    const float* bih = (const float*)d_in[5];
    const float* bhh = (const float*)d_in[6];
    float* out = (float*)d_out;

    char* ws = (char*)d_ws;
    f16*      wsW = (f16*)(ws + OFF_W);
    float*    wsB = (float*)(ws + OFF_B);
    f16*      hb0 = (f16*)(ws + OFF_H0);
    f16*      hb1 = (f16*)(ws + OFF_H1);
    float*    wsC = (float*)(ws + OFF_C);
    unsigned* bar = (unsigned*)(ws + OFF_BAR);

    lstm_init<<<2048, 256, 0, stream>>>(h0, c0, Wih, Whh, bih, bhh,
                                        wsW, wsB, hb0, hb1, wsC, bar);

    void* kargs[] = { (void*)&x, (void*)&wsW, (void*)&wsB, (void*)&hb0, (void*)&hb1,
                      (void*)&wsC, (void*)&out, (void*)&bar };
    hipLaunchCooperativeKernel((void*)lstm_main, dim3(256), dim3(512), kargs, 0, stream);
}

// Round 2
// 6490.864 us; speedup vs baseline: 1.5809x; 1.5809x over previous
//
#include <hip/hip_runtime.h>

// LSTM T=256, N=128, D=H=1024, L=2.  Persistent cooperative kernel:
// 256 WGs x 512 thr (1 WG/CU).  WG (layer l, slice s) owns hidden units
// [8s, 8s+8) => 32 gate cols, weights pinned in LDS (131.6KB).
// Iteration tau: layer0 step tau, layer1 step tau-1 -> ONE grid barrier/iter.
// Coherence: NO agent fences (they emit buffer_wbl2/buffer_inv = full L2
// writeback+invalidate per WG per iter -> 39us/iter in round 1).  Instead:
//  - barrier counters: RELAXED agent atomics (plain global_atomic sc1)
//  - h exchange BIG mode: time-unique slot per (layer,step); stores are
//    relaxed agent-scope (sc1 -> LLC, write-around local caches); loads are
//    plain cached loads (address never cached before writer finished,
//    so no stale line can exist; broadcast served from warm L2)
//  - fallback (small ws): double-buffered h, sc1 atomic loads

typedef _Float16 f16;
typedef f16  v8f16 __attribute__((ext_vector_type(8)));
typedef float v4f32 __attribute__((ext_vector_type(4)));

#define TSTEPS 256
#define SLOT   131072u                  /* h slot elems: 128x1024 f16 */

// ---------------- ws layouts (bytes) ----------------
// common: W fp16 then B fp32
#define SZ_W     (2u*4096u*2048u*2u)    /* 33554432 */
#define SZ_B     (2u*4096u*4u)
// BIG: hseq = 2 layers * 258 slots
#define SZ_HSEQ  (2u*258u*SLOT*2u)
#define SZ_C     (2u*128u*1024u*4u)
#define SZ_BAR   2048u
#define BIG_NEED ((size_t)SZ_W + SZ_B + SZ_HSEQ + SZ_C + SZ_BAR)
// OLD: two double-buffers
#define SZ_HDB   (2u*SLOT*2u)

__global__ void lstm_init(const float* __restrict__ h0, const float* __restrict__ c0,
                          const float* __restrict__ Wih, const float* __restrict__ Whh,
                          const float* __restrict__ bih, const float* __restrict__ bhh,
                          f16* __restrict__ wsW, float* __restrict__ wsB,
                          f16* __restrict__ h0dst0, f16* __restrict__ h0dst1,
                          float* __restrict__ wsC, unsigned* __restrict__ bar)
{
    size_t tid  = (size_t)blockIdx.x * blockDim.x + threadIdx.x;
    size_t nthr = (size_t)gridDim.x * blockDim.x;
    // weights: [l][col][k], k<1024 -> W_ih, k>=1024 -> W_hh
    for (size_t i = tid; i < 16777216u; i += nthr) {
        unsigned l = (unsigned)(i >> 23), rem = (unsigned)(i & 8388607u);
        unsigned col = rem >> 11, k = rem & 2047u;
        float v = (k < 1024u) ? Wih[(size_t)l*4194304u + (size_t)col*1024u + k]
                              : Whh[(size_t)l*4194304u + (size_t)col*1024u + (k-1024u)];
        wsW[i] = (f16)v;
    }
    for (size_t i = tid; i < 8192u; i += nthr) wsB[i] = bih[i] + bhh[i];
    for (size_t i = tid; i < 131072u; i += nthr) {
        h0dst0[i] = (f16)h0[i];
        h0dst1[i] = (f16)h0[131072u + i];
    }
    for (size_t i = tid; i < 262144u; i += nthr) wsC[i] = c0[i];
    for (size_t i = tid; i < 512u;    i += nthr) bar[i] = 0u;
}

__device__ __forceinline__ float sigmoid_fast(float v) { return 1.0f / (1.0f + __expf(-v)); }
__device__ __forceinline__ float tanh_fast(float v)    { return 1.0f - 2.0f / (__expf(2.0f*v) + 1.0f); }

__device__ __forceinline__ v8f16 cvt8(v4f32 lo, v4f32 hi) {
    v8f16 r;
    r[0]=(f16)lo[0]; r[1]=(f16)lo[1]; r[2]=(f16)lo[2]; r[3]=(f16)lo[3];
    r[4]=(f16)hi[0]; r[5]=(f16)hi[1]; r[6]=(f16)hi[2]; r[7]=(f16)hi[3];
    return r;
}

template<bool BIG>
__device__ __forceinline__ v8f16 loadA8(const f16* p) {
    if constexpr (BIG) {
        return *(const v8f16*)p;                       // plain cached load
    } else {
        unsigned long long a = __hip_atomic_load((const unsigned long long*)p,
                                 __ATOMIC_RELAXED, __HIP_MEMORY_SCOPE_AGENT);
        unsigned long long b = __hip_atomic_load(((const unsigned long long*)p) + 1,
                                 __ATOMIC_RELAXED, __HIP_MEMORY_SCOPE_AGENT);
        union { unsigned long long u[2]; v8f16 v; } c; c.u[0]=a; c.u[1]=b; return c.v;
    }
}

__device__ __forceinline__ void storeH(f16* p, float hv) {
    union { f16 h; unsigned short u; } c; c.h = (f16)hv;
    __hip_atomic_store((unsigned short*)p, c.u, __ATOMIC_RELAXED, __HIP_MEMORY_SCOPE_AGENT);
}

// fence-free hierarchical grid barrier (16 groups of 16 + root)
__device__ __forceinline__ void grid_barrier_fn(unsigned* bar, int wgid, unsigned target) {
    __syncthreads();   // compiler emits s_waitcnt vmcnt(0) before s_barrier: stores drained
    if (threadIdx.x == 0) {
        unsigned* grp  = bar + ((wgid >> 4) << 4);
        unsigned* root = bar + 384;
        unsigned* gen  = bar + 448;
        unsigned a = __hip_atomic_fetch_add(grp, 1u, __ATOMIC_RELAXED, __HIP_MEMORY_SCOPE_AGENT);
        if (a == 15u) {
            __hip_atomic_store(grp, 0u, __ATOMIC_RELAXED, __HIP_MEMORY_SCOPE_AGENT);
            unsigned r = __hip_atomic_fetch_add(root, 1u, __ATOMIC_RELAXED, __HIP_MEMORY_SCOPE_AGENT);
            if (r == 15u) {
                __hip_atomic_store(root, 0u, __ATOMIC_RELAXED, __HIP_MEMORY_SCOPE_AGENT);
                __hip_atomic_store(gen, target, __ATOMIC_RELAXED, __HIP_MEMORY_SCOPE_AGENT);
            }
        }
        while (__hip_atomic_load(gen, __ATOMIC_RELAXED, __HIP_MEMORY_SCOPE_AGENT) < target) {
            __builtin_amdgcn_s_sleep(2);
        }
    }
    __syncthreads();
}

template<bool BIG>
__global__ void __launch_bounds__(512)
lstm_main(const float* __restrict__ x, const f16* __restrict__ wsW,
          const float* __restrict__ wsB,
          f16* __restrict__ hb0, f16* __restrict__ hb1,     // OLD mode
          f16* __restrict__ hseq,                            // BIG mode
          float* __restrict__ wsC, float* __restrict__ out, unsigned* __restrict__ bar)
{
    __shared__ f16   wlds[32][2056];   // 32 gate cols x K=2048 (+8 pad)
    __shared__ float glds[128][33];    // gate scratch

    const int tid   = threadIdx.x;
    const int wgid  = blockIdx.x;
    const int layer = wgid >> 7;
    const int s     = wgid & 127;
    const int lane  = tid & 63;
    const int wave  = tid >> 6;
    const int quad  = lane >> 4;
    const int l15   = lane & 15;
    const int rb    = wave & 3;        // row block: rows [32rb, 32rb+32)
    const int ks    = wave >> 2;       // k split

    for (int idx = tid; idx < 8192; idx += 512) {
        int cc = idx >> 8;
        int k8 = (idx & 255) << 3;
        int col = ((cc >> 3) << 10) + (s << 3) + (cc & 7);
        *(v8f16*)(&wlds[cc][k8]) =
            *(const v8f16*)(wsW + (((size_t)(layer*4096 + col)) << 11) + k8);
    }

    const int u  = tid & 7;
    const int jg = (s << 3) + u;
    const float bi = wsB[layer*4096 +        jg];
    const float bf = wsB[layer*4096 + 1024 + jg];
    const float bg = wsB[layer*4096 + 2048 + jg];
    const float bo = wsB[layer*4096 + 3072 + jg];
    const int n1 = tid >> 3;

    __syncthreads();

    const int kq   = quad << 3;
    const int row0 = (rb << 5) + l15;

    for (int tau = 0; tau <= TSTEPS; ++tau) {
        const int rbuf = tau & 1, wbuf = rbuf ^ 1;
        const bool active = layer ? (tau >= 1) : (tau < TSTEPS);
        if (active) {
            const int t = tau - layer;
            v4f32 acc[2][2] = {};

            if (ks == 0 && layer == 0) {
                // layer0 input half: x[t] fp32 -> fp16 on the fly (x is read-only: always cached)
                const float* p0 = x + (((size_t)t) << 17) + ((size_t)row0 << 10) + kq;
                const float* p1 = p0 + (16 << 10);
                #pragma unroll 4
                for (int k = 0; k < 1024; k += 32) {
                    v4f32 w0 = *(const v4f32*)(p0 + k), w1 = *(const v4f32*)(p0 + k + 4);
                    v4f32 y0 = *(const v4f32*)(p1 + k), y1 = *(const v4f32*)(p1 + k + 4);
                    v8f16 a0 = cvt8(w0, w1);
                    v8f16 a1 = cvt8(y0, y1);
                    v8f16 b0 = *(const v8f16*)(&wlds[l15     ][k + kq]);
                    v8f16 b1 = *(const v8f16*)(&wlds[16 + l15][k + kq]);
                    acc[0][0] = __builtin_amdgcn_mfma_f32_16x16x32_f16(a0, b0, acc[0][0], 0, 0, 0);
                    acc[0][1] = __builtin_amdgcn_mfma_f32_16x16x32_f16(a0, b1, acc[0][1], 0, 0, 0);
                    acc[1][0] = __builtin_amdgcn_mfma_f32_16x16x32_f16(a1, b0, acc[1][0], 0, 0, 0);
                    acc[1][1] = __builtin_amdgcn_mfma_f32_16x16x32_f16(a1, b1, acc[1][1], 0, 0, 0);
                }
            } else {
                const f16* base;
                if constexpr (BIG) {
                    // slots: h_l[t] lives at slot t+1 of layer l; slot0 = initial
                    // layer0 rec: slot_0[tau]; layer1 input: slot_0[tau]; layer1 rec: slot_1[tau-1]
                    base = (ks == 0) ? (hseq + (size_t)tau * SLOT)                 // layer1 input
                         : (layer ? (hseq + (size_t)(258 + tau - 1) * SLOT)        // layer1 rec
                                  : (hseq + (size_t)tau * SLOT));                  // layer0 rec
                } else {
                    base = (ks == 0) ? (hb0 + rbuf * SLOT)
                                     : ((layer ? hb1 : hb0) + rbuf * SLOT);
                }
                const f16* p0 = base + (row0 << 10) + kq;
                const f16* p1 = p0 + (16 << 10);
                #pragma unroll 8
                for (int k = 0; k < 1024; k += 32) {
                    v8f16 a0 = loadA8<BIG>(p0 + k);
                    v8f16 a1 = loadA8<BIG>(p1 + k);
                    v8f16 b0 = *(const v8f16*)(&wlds[l15     ][(ks << 10) + k + kq]);
                    v8f16 b1 = *(const v8f16*)(&wlds[16 + l15][(ks << 10) + k + kq]);
                    acc[0][0] = __builtin_amdgcn_mfma_f32_16x16x32_f16(a0, b0, acc[0][0], 0, 0, 0);
                    acc[0][1] = __builtin_amdgcn_mfma_f32_16x16x32_f16(a0, b1, acc[0][1], 0, 0, 0);
                    acc[1][0] = __builtin_amdgcn_mfma_f32_16x16x32_f16(a1, b0, acc[1][0], 0, 0, 0);
                    acc[1][1] = __builtin_amdgcn_mfma_f32_16x16x32_f16(a1, b1, acc[1][1], 0, 0, 0);
                }
            }

            // reduce the 2 K-splits through LDS (C layout: row=quad*4+r, col=l15)
            if (ks == 0) {
                #pragma unroll
                for (int mt = 0; mt < 2; ++mt) {
                    int rrow = (rb << 5) + (mt << 4) + (quad << 2);
                    #pragma unroll
                    for (int r = 0; r < 4; ++r) {
                        glds[rrow + r][l15     ] = acc[mt][0][r];
                        glds[rrow + r][16 + l15] = acc[mt][1][r];
                    }
                }
            }
            __syncthreads();
            if (ks == 1) {
                #pragma unroll
                for (int mt = 0; mt < 2; ++mt) {
                    int rrow = (rb << 5) + (mt << 4) + (quad << 2);
                    #pragma unroll
                    for (int r = 0; r < 4; ++r) {
                        glds[rrow + r][l15     ] += acc[mt][0][r];
                        glds[rrow + r][16 + l15] += acc[mt][1][r];
                    }
                }
            }
            __syncthreads();

            #pragma unroll
            for (int pp = 0; pp < 2; ++pp) {
                int n = n1 + (pp << 6);
                float gi = glds[n][u]      + bi;
                float gf = glds[n][8 + u]  + bf;
                float gg = glds[n][16 + u] + bg;
                float go = glds[n][24 + u] + bo;
                float si = sigmoid_fast(gi), sf = sigmoid_fast(gf), so = sigmoid_fast(go);
                float tg = tanh_fast(gg);
                float* cp = wsC + (layer << 17) + (n << 10) + jg;
                float cn = sf * (*cp) + si * tg;
                *cp = cn;
                float hv = so * tanh_fast(cn);
                if (layer == 1 && t == TSTEPS - 1) {
                    out[(n << 10) + jg] = hv;
                } else {
                    f16* hw;
                    if constexpr (BIG) {
                        // layer0 writes slot_0[tau+1]; layer1 writes slot_1[tau]
                        hw = layer ? (hseq + (size_t)(258 + tau) * SLOT)
                                   : (hseq + (size_t)(tau + 1) * SLOT);
                    } else {
                        hw = (layer ? hb1 : hb0) + wbuf * SLOT;
                    }
                    storeH(hw + (n << 10) + jg, hv);
                }
            }
        }
        grid_barrier_fn(bar, wgid, (unsigned)(tau + 1));
    }
}

extern "C" void kernel_launch(void* const* d_in, const int* in_sizes, int n_in,
                              void* d_out, int out_size, void* d_ws, size_t ws_size,
                              hipStream_t stream) {
    const float* x   = (const float*)d_in[0];
    const float* h0  = (const float*)d_in[1];
    const float* c0  = (const float*)d_in[2];
    const float* Wih = (const float*)d_in[3];
    const float* Whh = (const float*)d_in[4];
    const float* bih = (const float*)d_in[5];
    const float* bhh = (const float*)d_in[6];
    float* out = (float*)d_out;

    char* ws = (char*)d_ws;
    const bool big = (ws_size >= BIG_NEED);

    f16*   wsW = (f16*)(ws);
    float* wsB = (float*)(ws + SZ_W);
    char*  p   = ws + SZ_W + SZ_B;

    f16 *hb0 = nullptr, *hb1 = nullptr, *hseq = nullptr;
    f16 *h0dst0, *h0dst1;
    float* wsC;
    unsigned* bar;

    if (big) {
        hseq = (f16*)p;                 p += SZ_HSEQ;
        wsC  = (float*)p;               p += SZ_C;
        bar  = (unsigned*)p;
        h0dst0 = hseq;                              // slot_0[0]
        h0dst1 = hseq + (size_t)258 * SLOT;         // slot_1[0]
    } else {
        hb0 = (f16*)p;                  p += SZ_HDB;
        hb1 = (f16*)p;                  p += SZ_HDB;
        wsC  = (float*)p;               p += SZ_C;
        bar  = (unsigned*)p;
        h0dst0 = hb0;                               // parity-0
        h0dst1 = hb1 + SLOT;                        // parity-1
    }

    lstm_init<<<2048, 256, 0, stream>>>(h0, c0, Wih, Whh, bih, bhh,
                                        wsW, wsB, h0dst0, h0dst1, wsC, bar);

    void* kargs[] = { (void*)&x, (void*)&wsW, (void*)&wsB, (void*)&hb0, (void*)&hb1,
                      (void*)&hseq, (void*)&wsC, (void*)&out, (void*)&bar };
    if (big) {
        hipLaunchCooperativeKernel((void*)&lstm_main<true>, dim3(256), dim3(512), kargs, 0, stream);
    } else {
        hipLaunchCooperativeKernel((void*)&lstm_main<false>, dim3(256), dim3(512), kargs, 0, stream);
    }
}

// Round 3
// 5154.153 us; speedup vs baseline: 1.9908x; 1.2593x over previous
//
#include <hip/hip_runtime.h>

// LSTM T=256, N=128, D=H=1024, L=2.  Persistent cooperative kernel, 256 WGs x 512.
// WG (layer l, slice s) owns hidden units [8s,8s+8) => 32 gate cols, weights in LDS.
// Round-3 changes vs round-2:
//  * DECOUPLED per-layer barriers (elastic pipeline): L0 only syncs among its own
//    128 WGs; L1 waits on (gen0 >= t+1, gen1 >= t). Time-unique h slots make any
//    lag safe. No global 256-WG lockstep.
//  * x preconverted to fp16 in init (mode2) -> same fp16 k-loop for all A sources,
//    no per-iter cvt VALU tax, half the bytes.
//  * x[t+1] prefetched into the local XCD's L2 during step t via global_load_lds
//    into a scratch sink (x is recurrence-independent; team of 16 WGs per XCD
//    covers all 128 rows: WG s prefetches rows [(s>>3)*8, +8)).
//  * c-state lives in registers (2 floats/thread) -- zero c memory traffic.
//  * h slot stores: relaxed agent-scope (sc1, write-around); loads plain cached
//    (slot address untouched before producer flag -> no stale line possible).

typedef _Float16 f16;
typedef f16  v8f16 __attribute__((ext_vector_type(8)));
typedef float v4f32 __attribute__((ext_vector_type(4)));

#define TSTEPS 256
#define SLOT   131072u
static constexpr size_t HS_BANK = (size_t)258 * SLOT;   // elems per layer bank

#define SZ_W     ((size_t)2*4096*2048*2)   /* fp16 weights [l][col][k2048] */
#define SZ_B     ((size_t)2*4096*4)        /* fused bias fp32 */
#define SZ_HSEQ  ((size_t)2*258*SLOT*2)    /* h slots, 2 banks, fp16 */
#define SZ_BAR   ((size_t)4096)
#define SZ_XF    ((size_t)256*128*1024*2)  /* x in fp16 */
#define NEED1    (SZ_W + SZ_B + SZ_HSEQ + SZ_BAR)
#define NEED2    (NEED1 + SZ_XF)

typedef const __attribute__((address_space(1))) void* gas_t;
typedef __attribute__((address_space(3))) void* las_t;

__global__ void lstm_init(const float* __restrict__ x,
                          const float* __restrict__ h0,
                          const float* __restrict__ Wih, const float* __restrict__ Whh,
                          const float* __restrict__ bih, const float* __restrict__ bhh,
                          f16* __restrict__ wsW, float* __restrict__ wsB,
                          f16* __restrict__ hseq, unsigned* __restrict__ bar,
                          f16* __restrict__ xf, int do_xf)
{
    size_t tid  = (size_t)blockIdx.x * blockDim.x + threadIdx.x;
    size_t nthr = (size_t)gridDim.x * blockDim.x;
    // weights: [l][col][k], k<1024 -> W_ih, k>=1024 -> W_hh
    for (size_t i = tid; i < 16777216u; i += nthr) {
        unsigned l = (unsigned)(i >> 23), rem = (unsigned)(i & 8388607u);
        unsigned col = rem >> 11, k = rem & 2047u;
        float v = (k < 1024u) ? Wih[(size_t)l*4194304u + (size_t)col*1024u + k]
                              : Whh[(size_t)l*4194304u + (size_t)col*1024u + (k-1024u)];
        wsW[i] = (f16)v;
    }
    for (size_t i = tid; i < 8192u; i += nthr) wsB[i] = bih[i] + bhh[i];
    for (size_t i = tid; i < 131072u; i += nthr) {
        hseq[i]           = (f16)h0[i];             // layer0 slot 0
        hseq[HS_BANK + i] = (f16)h0[131072u + i];   // layer1 slot 0
    }
    for (size_t i = tid; i < 1024u; i += nthr) bar[i] = 0u;
    if (do_xf) {
        for (size_t i = tid; i < 33554432u; i += nthr) xf[i] = (f16)x[i];
    }
}

__device__ __forceinline__ float sigmoid_fast(float v) { return 1.0f / (1.0f + __expf(-v)); }
__device__ __forceinline__ float tanh_fast(float v)    { return 1.0f - 2.0f / (__expf(2.0f*v) + 1.0f); }

__device__ __forceinline__ v8f16 cvt8(v4f32 lo, v4f32 hi) {
    v8f16 r;
    r[0]=(f16)lo[0]; r[1]=(f16)lo[1]; r[2]=(f16)lo[2]; r[3]=(f16)lo[3];
    r[4]=(f16)hi[0]; r[5]=(f16)hi[1]; r[6]=(f16)hi[2]; r[7]=(f16)hi[3];
    return r;
}

__device__ __forceinline__ void storeH(f16* p, float hv) {
    union { f16 h; unsigned short u; } c; c.h = (f16)hv;
    __hip_atomic_store((unsigned short*)p, c.u, __ATOMIC_RELAXED, __HIP_MEMORY_SCOPE_AGENT);
}

__device__ __forceinline__ unsigned ld_gen(const unsigned* p) {
    return __hip_atomic_load(p, __ATOMIC_RELAXED, __HIP_MEMORY_SCOPE_AGENT);
}

// per-layer arrive: 8 group counters (16 WGs each), root, gen (all monotone)
__device__ __forceinline__ void arrive(unsigned* base, int s, unsigned t1) {
    unsigned* grp  = base + ((s >> 4) << 4);
    unsigned* root = base + 128;
    unsigned* gen  = base + 144;
    unsigned a = __hip_atomic_fetch_add(grp, 1u, __ATOMIC_RELAXED, __HIP_MEMORY_SCOPE_AGENT);
    if (a == 16u*t1 - 1u) {
        unsigned r = __hip_atomic_fetch_add(root, 1u, __ATOMIC_RELAXED, __HIP_MEMORY_SCOPE_AGENT);
        if (r == 8u*t1 - 1u)
            __hip_atomic_store(gen, t1, __ATOMIC_RELAXED, __HIP_MEMORY_SCOPE_AGENT);
    }
}

__device__ __forceinline__ void kloop_f16(const f16* p0, const f16* p1,
                                          const f16 (*wl)[2056], int l15, int kq, int kofs,
                                          v4f32 acc[2][2])
{
    #pragma unroll 8
    for (int k = 0; k < 1024; k += 32) {
        v8f16 a0 = *(const v8f16*)(p0 + k);
        v8f16 a1 = *(const v8f16*)(p1 + k);
        v8f16 b0 = *(const v8f16*)(&wl[l15     ][kofs + k + kq]);
        v8f16 b1 = *(const v8f16*)(&wl[16 + l15][kofs + k + kq]);
        acc[0][0] = __builtin_amdgcn_mfma_f32_16x16x32_f16(a0, b0, acc[0][0], 0, 0, 0);
        acc[0][1] = __builtin_amdgcn_mfma_f32_16x16x32_f16(a0, b1, acc[0][1], 0, 0, 0);
        acc[1][0] = __builtin_amdgcn_mfma_f32_16x16x32_f16(a1, b0, acc[1][0], 0, 0, 0);
        acc[1][1] = __builtin_amdgcn_mfma_f32_16x16x32_f16(a1, b1, acc[1][1], 0, 0, 0);
    }
}

__device__ __forceinline__ void reduce_splits(v4f32 acc[2][2], float (*gl)[33],
                                              int rb, int quad, int l15, int ks)
{
    if (ks == 0) {
        #pragma unroll
        for (int mt = 0; mt < 2; ++mt) {
            int rrow = (rb << 5) + (mt << 4) + (quad << 2);
            #pragma unroll
            for (int r = 0; r < 4; ++r) {
                gl[rrow + r][l15     ] = acc[mt][0][r];
                gl[rrow + r][16 + l15] = acc[mt][1][r];
            }
        }
    }
    __syncthreads();
    if (ks == 1) {
        #pragma unroll
        for (int mt = 0; mt < 2; ++mt) {
            int rrow = (rb << 5) + (mt << 4) + (quad << 2);
            #pragma unroll
            for (int r = 0; r < 4; ++r) {
                gl[rrow + r][l15     ] += acc[mt][0][r];
                gl[rrow + r][16 + l15] += acc[mt][1][r];
            }
        }
    }
    __syncthreads();
}

__device__ __forceinline__ void cell2(const float (*gl)[33], int n1, int u,
                                      float bi, float bf, float bg, float bo,
                                      float& cr0, float& cr1, float& h0o, float& h1o)
{
    {
        float gi = gl[n1][u]      + bi;
        float gf = gl[n1][8 + u]  + bf;
        float gg = gl[n1][16 + u] + bg;
        float go = gl[n1][24 + u] + bo;
        float cn = sigmoid_fast(gf) * cr0 + sigmoid_fast(gi) * tanh_fast(gg);
        cr0 = cn;
        h0o = sigmoid_fast(go) * tanh_fast(cn);
    }
    {
        int n = n1 + 64;
        float gi = gl[n][u]      + bi;
        float gf = gl[n][8 + u]  + bf;
        float gg = gl[n][16 + u] + bg;
        float go = gl[n][24 + u] + bo;
        float cn = sigmoid_fast(gf) * cr1 + sigmoid_fast(gi) * tanh_fast(gg);
        cr1 = cn;
        h1o = sigmoid_fast(go) * tanh_fast(cn);
    }
}

template<bool XF16>
__global__ void __launch_bounds__(512)
lstm_main(const float* __restrict__ x, const f16* __restrict__ xf,
          const f16* __restrict__ wsW, const float* __restrict__ wsB,
          f16* __restrict__ hseq, const float* __restrict__ c0,
          float* __restrict__ out, unsigned* __restrict__ bar)
{
    __shared__ f16   wlds[32][2056];   // 131584 B
    __shared__ float glds[128][33];    //  16896 B
    __shared__ f16   pfb[2048];        //   4096 B prefetch sink

    const int tid   = threadIdx.x;
    const int wgid  = blockIdx.x;
    const int layer = wgid >> 7;
    const int s     = wgid & 127;
    const int lane  = tid & 63;
    const int wave  = tid >> 6;
    const int quad  = lane >> 4;
    const int l15   = lane & 15;
    const int rb    = wave & 3;        // rows [32rb, 32rb+32)
    const int ks    = wave >> 2;       // K split

    for (int idx = tid; idx < 8192; idx += 512) {
        int cc = idx >> 8;
        int k8 = (idx & 255) << 3;
        int col = ((cc >> 3) << 10) + (s << 3) + (cc & 7);
        *(v8f16*)(&wlds[cc][k8]) =
            *(const v8f16*)(wsW + (((size_t)(layer*4096 + col)) << 11) + k8);
    }

    const int u  = tid & 7;
    const int jg = (s << 3) + u;
    const float bi = wsB[layer*4096 +        jg];
    const float bf = wsB[layer*4096 + 1024 + jg];
    const float bg = wsB[layer*4096 + 2048 + jg];
    const float bo = wsB[layer*4096 + 3072 + jg];
    const int n1 = tid >> 3;
    float cr0 = c0[((size_t)layer << 17) + ((size_t)n1 << 10) + jg];
    float cr1 = c0[((size_t)layer << 17) + ((size_t)(n1 + 64) << 10) + jg];

    __syncthreads();

    const int kq   = quad << 3;
    const int row0 = (rb << 5) + l15;
    const int arow = (row0 << 10) + kq;

    f16* h0b = hseq;
    f16* h1b = hseq + HS_BANK;
    unsigned* bar0 = bar;
    unsigned* bar1 = bar + 256;
    unsigned* gen0 = bar + 144;
    unsigned* gen1 = bar + 256 + 144;

    if (layer == 0) {
        for (int t = 0; t < TSTEPS; ++t) {
            if (t > 0) {
                if (tid == 0) {
                    while (ld_gen(gen0) < (unsigned)t) __builtin_amdgcn_s_sleep(2);
                }
                __syncthreads();
            }

            // prefetch x[t+1] rows [(s>>3)*8, +8) into local L2 (team of 16 WGs
            // per XCD covers all 128 rows); sink LDS, data only warms caches.
            {
                const int tn = (t < TSTEPS - 1) ? t + 1 : t;
                if (XF16) {
                    if (tid < 128) {
                        las_t lp = (las_t)&pfb[(tid >> 6) << 9];
                        const f16* gx = xf + (size_t)tn * 131072u
                                      + (size_t)((s >> 3) << 3) * 1024u + ((size_t)tid << 3);
                        #pragma unroll
                        for (int j = 0; j < 8; ++j)
                            __builtin_amdgcn_global_load_lds((gas_t)(gx + (j << 10)), lp, 16, 0, 0);
                    }
                } else {
                    if (tid < 256) {
                        las_t lp = (las_t)&pfb[(tid >> 6) << 9];
                        const float* gx = x + (size_t)tn * 131072u
                                        + (size_t)((s >> 3) << 3) * 1024u + ((size_t)tid << 2);
                        #pragma unroll
                        for (int j = 0; j < 8; ++j)
                            __builtin_amdgcn_global_load_lds((gas_t)(gx + (j << 10)), lp, 16, 0, 0);
                    }
                }
            }

            v4f32 acc[2][2] = {};
            if (ks == 0) {
                if (XF16) {
                    const f16* p0 = xf + ((size_t)t << 17) + arow;
                    kloop_f16(p0, p0 + (16 << 10), wlds, l15, kq, 0, acc);
                } else {
                    const float* p0 = x + ((size_t)t << 17) + arow;
                    const float* p1 = p0 + (16 << 10);
                    #pragma unroll 4
                    for (int k = 0; k < 1024; k += 32) {
                        v4f32 w0 = *(const v4f32*)(p0 + k), w1 = *(const v4f32*)(p0 + k + 4);
                        v4f32 y0 = *(const v4f32*)(p1 + k), y1 = *(const v4f32*)(p1 + k + 4);
                        v8f16 a0 = cvt8(w0, w1);
                        v8f16 a1 = cvt8(y0, y1);
                        v8f16 b0 = *(const v8f16*)(&wlds[l15     ][k + kq]);
                        v8f16 b1 = *(const v8f16*)(&wlds[16 + l15][k + kq]);
                        acc[0][0] = __builtin_amdgcn_mfma_f32_16x16x32_f16(a0, b0, acc[0][0], 0, 0, 0);
                        acc[0][1] = __builtin_amdgcn_mfma_f32_16x16x32_f16(a0, b1, acc[0][1], 0, 0, 0);
                        acc[1][0] = __builtin_amdgcn_mfma_f32_16x16x32_f16(a1, b0, acc[1][0], 0, 0, 0);
                        acc[1][1] = __builtin_amdgcn_mfma_f32_16x16x32_f16(a1, b1, acc[1][1], 0, 0, 0);
                    }
                }
            } else {
                const f16* p0 = h0b + (size_t)t * SLOT + arow;
                kloop_f16(p0, p0 + (16 << 10), wlds, l15, kq, 1024, acc);
            }

            reduce_splits(acc, glds, rb, quad, l15, ks);

            float hv0, hv1;
            cell2(glds, n1, u, bi, bf, bg, bo, cr0, cr1, hv0, hv1);
            f16* hw = h0b + (size_t)(t + 1) * SLOT;
            storeH(hw + (n1 << 10) + jg, hv0);
            storeH(hw + ((n1 + 64) << 10) + jg, hv1);

            __syncthreads();                       // drains vmcnt: stores at LLC
            if (tid == 0) arrive(bar0, s, (unsigned)(t + 1));
        }
    } else {
        for (int t = 0; t < TSTEPS; ++t) {
            if (tid == 0) {
                while (ld_gen(gen0) < (unsigned)(t + 1)) __builtin_amdgcn_s_sleep(2);
                if (t > 0) {
                    while (ld_gen(gen1) < (unsigned)t) __builtin_amdgcn_s_sleep(2);
                }
            }
            __syncthreads();

            v4f32 acc[2][2] = {};
            if (ks == 0) {
                const f16* p0 = h0b + (size_t)(t + 1) * SLOT + arow;   // layer-0 output, step t
                kloop_f16(p0, p0 + (16 << 10), wlds, l15, kq, 0, acc);
            } else {
                const f16* p0 = h1b + (size_t)t * SLOT + arow;         // own recurrence
                kloop_f16(p0, p0 + (16 << 10), wlds, l15, kq, 1024, acc);
            }

            reduce_splits(acc, glds, rb, quad, l15, ks);

            float hv0, hv1;
            cell2(glds, n1, u, bi, bf, bg, bo, cr0, cr1, hv0, hv1);
            if (t < TSTEPS - 1) {
                f16* hw = h1b + (size_t)(t + 1) * SLOT;
                storeH(hw + (n1 << 10) + jg, hv0);
                storeH(hw + ((n1 + 64) << 10) + jg, hv1);
                __syncthreads();
                if (tid == 0) arrive(bar1, s, (unsigned)(t + 1));
            } else {
                out[(n1 << 10) + jg] = hv0;
                out[((n1 + 64) << 10) + jg] = hv1;
            }
        }
    }
}

extern "C" void kernel_launch(void* const* d_in, const int* in_sizes, int n_in,
                              void* d_out, int out_size, void* d_ws, size_t ws_size,
                              hipStream_t stream) {
    const float* x   = (const float*)d_in[0];
    const float* h0  = (const float*)d_in[1];
    const float* c0  = (const float*)d_in[2];
    const float* Wih = (const float*)d_in[3];
    const float* Whh = (const float*)d_in[4];
    const float* bih = (const float*)d_in[5];
    const float* bhh = (const float*)d_in[6];
    float* out = (float*)d_out;

    char* ws = (char*)d_ws;
    const bool xf16 = (ws_size >= NEED2);

    f16*      wsW  = (f16*)ws;
    float*    wsB  = (float*)(ws + SZ_W);
    f16*      hseq = (f16*)(ws + SZ_W + SZ_B);
    unsigned* bar  = (unsigned*)(ws + SZ_W + SZ_B + SZ_HSEQ);
    f16*      xf   = (f16*)(ws + NEED1);
    int do_xf = xf16 ? 1 : 0;

    lstm_init<<<2048, 256, 0, stream>>>(x, h0, Wih, Whh, bih, bhh,
                                        wsW, wsB, hseq, bar, xf, do_xf);

    void* kargs[] = { (void*)&x, (void*)&xf, (void*)&wsW, (void*)&wsB,
                      (void*)&hseq, (void*)&c0, (void*)&out, (void*)&bar };
    if (xf16) {
        hipLaunchCooperativeKernel((void*)&lstm_main<true>, dim3(256), dim3(512), kargs, 0, stream);
    } else {
        hipLaunchCooperativeKernel((void*)&lstm_main<false>, dim3(256), dim3(512), kargs, 0, stream);
    }
}

// Round 4
// 5113.949 us; speedup vs baseline: 2.0065x; 1.0079x over previous
//
#include <hip/hip_runtime.h>

// LSTM T=256, N=128, D=H=1024, L=2.  Persistent cooperative kernel, 256 WGs x 512.
// WG (layer l, slice s) owns hidden units [8s,8s+8) => 32 gate cols, weights in LDS.
// Round-4 structure: per step, the x-part (x[t] @ Wih, K=1024) is computed BEFORE
// the recurrence flag poll (it has no dependency); only the h-part (h[t] @ Whh)
// is on the dependent path.  Single-counter-per-layer barrier (1 LLC round trip).
// h exchange: time-unique slots, agent-scope (sc1) stores staged through LDS as
// 16-B row chunks; consumers use plain cached loads (slot address never cached
// before the flag -> no stale line).  c-state in registers.  glds stride 36
// (2-way max = free).  No prefetch (vmcnt/LDS-alias pollution).

typedef _Float16 f16;
typedef f16  v8f16 __attribute__((ext_vector_type(8)));
typedef float v4f32 __attribute__((ext_vector_type(4)));

#define TSTEPS 256
#define SLOT   131072u
static constexpr size_t HS_BANK = (size_t)258 * SLOT;   // elems per layer bank

#define SZ_W     ((size_t)2*4096*2048*2)   /* fp16 weights [l][col][k2048] */
#define SZ_B     ((size_t)2*4096*4)        /* fused bias fp32 */
#define SZ_HSEQ  ((size_t)2*258*SLOT*2)    /* h slots, 2 banks, fp16 */
#define SZ_BAR   ((size_t)4096)
#define SZ_XF    ((size_t)256*128*1024*2)  /* x in fp16 */
#define NEED1    (SZ_W + SZ_B + SZ_HSEQ + SZ_BAR)
#define NEED2    (NEED1 + SZ_XF)

__global__ void lstm_init(const float* __restrict__ x,
                          const float* __restrict__ h0,
                          const float* __restrict__ Wih, const float* __restrict__ Whh,
                          const float* __restrict__ bih, const float* __restrict__ bhh,
                          f16* __restrict__ wsW, float* __restrict__ wsB,
                          f16* __restrict__ hseq, unsigned* __restrict__ bar,
                          f16* __restrict__ xf, int do_xf)
{
    size_t tid  = (size_t)blockIdx.x * blockDim.x + threadIdx.x;
    size_t nthr = (size_t)gridDim.x * blockDim.x;
    // weights: [l][col][k], k<1024 -> W_ih, k>=1024 -> W_hh
    for (size_t i = tid; i < 16777216u; i += nthr) {
        unsigned l = (unsigned)(i >> 23), rem = (unsigned)(i & 8388607u);
        unsigned col = rem >> 11, k = rem & 2047u;
        float v = (k < 1024u) ? Wih[(size_t)l*4194304u + (size_t)col*1024u + k]
                              : Whh[(size_t)l*4194304u + (size_t)col*1024u + (k-1024u)];
        wsW[i] = (f16)v;
    }
    for (size_t i = tid; i < 8192u; i += nthr) wsB[i] = bih[i] + bhh[i];
    for (size_t i = tid; i < 131072u; i += nthr) {
        hseq[i]           = (f16)h0[i];             // layer0 slot 0
        hseq[HS_BANK + i] = (f16)h0[131072u + i];   // layer1 slot 0
    }
    for (size_t i = tid; i < 512u; i += nthr) bar[i] = 0u;
    if (do_xf) {
        for (size_t i = tid; i < 33554432u; i += nthr) xf[i] = (f16)x[i];
    }
}

__device__ __forceinline__ float sigmoid_fast(float v) { return 1.0f / (1.0f + __expf(-v)); }
__device__ __forceinline__ float tanh_fast(float v)    { return 1.0f - 2.0f / (__expf(2.0f*v) + 1.0f); }

__device__ __forceinline__ v8f16 cvt8(v4f32 lo, v4f32 hi) {
    v8f16 r;
    r[0]=(f16)lo[0]; r[1]=(f16)lo[1]; r[2]=(f16)lo[2]; r[3]=(f16)lo[3];
    r[4]=(f16)hi[0]; r[5]=(f16)hi[1]; r[6]=(f16)hi[2]; r[7]=(f16)hi[3];
    return r;
}

__device__ __forceinline__ unsigned ld_cnt(const unsigned* p) {
    return __hip_atomic_load(p, __ATOMIC_RELAXED, __HIP_MEMORY_SCOPE_AGENT);
}

// 16-iteration K-loop over a 512-half K-slice (both phases accumulate into acc)
__device__ __forceinline__ void kloop16(const f16* p0, const f16* p1,
                                        const f16 (*wl)[2056], int l15, int kq, int kofs,
                                        v4f32 acc[2][2])
{
    #pragma unroll
    for (int k = 0; k < 512; k += 32) {
        v8f16 a0 = *(const v8f16*)(p0 + k);
        v8f16 a1 = *(const v8f16*)(p1 + k);
        v8f16 b0 = *(const v8f16*)(&wl[l15     ][kofs + k + kq]);
        v8f16 b1 = *(const v8f16*)(&wl[16 + l15][kofs + k + kq]);
        acc[0][0] = __builtin_amdgcn_mfma_f32_16x16x32_f16(a0, b0, acc[0][0], 0, 0, 0);
        acc[0][1] = __builtin_amdgcn_mfma_f32_16x16x32_f16(a0, b1, acc[0][1], 0, 0, 0);
        acc[1][0] = __builtin_amdgcn_mfma_f32_16x16x32_f16(a1, b0, acc[1][0], 0, 0, 0);
        acc[1][1] = __builtin_amdgcn_mfma_f32_16x16x32_f16(a1, b1, acc[1][1], 0, 0, 0);
    }
}

__device__ __forceinline__ void reduce_splits(v4f32 acc[2][2], float (*gl)[36],
                                              int rb, int quad, int l15, int ks)
{
    if (ks == 0) {
        #pragma unroll
        for (int mt = 0; mt < 2; ++mt) {
            int rrow = (rb << 5) + (mt << 4) + (quad << 2);
            #pragma unroll
            for (int r = 0; r < 4; ++r) {
                gl[rrow + r][l15     ] = acc[mt][0][r];
                gl[rrow + r][16 + l15] = acc[mt][1][r];
            }
        }
    }
    __syncthreads();
    if (ks == 1) {
        #pragma unroll
        for (int mt = 0; mt < 2; ++mt) {
            int rrow = (rb << 5) + (mt << 4) + (quad << 2);
            #pragma unroll
            for (int r = 0; r < 4; ++r) {
                gl[rrow + r][l15     ] += acc[mt][0][r];
                gl[rrow + r][16 + l15] += acc[mt][1][r];
            }
        }
    }
    __syncthreads();
}

__device__ __forceinline__ void cell2(const float (*gl)[36], int n1, int u,
                                      float bi, float bf, float bg, float bo,
                                      float& cr0, float& cr1, float& h0o, float& h1o)
{
    {
        float gi = gl[n1][u]      + bi;
        float gf = gl[n1][8 + u]  + bf;
        float gg = gl[n1][16 + u] + bg;
        float go = gl[n1][24 + u] + bo;
        float cn = sigmoid_fast(gf) * cr0 + sigmoid_fast(gi) * tanh_fast(gg);
        cr0 = cn;
        h0o = sigmoid_fast(go) * tanh_fast(cn);
    }
    {
        int n = n1 + 64;
        float gi = gl[n][u]      + bi;
        float gf = gl[n][8 + u]  + bf;
        float gg = gl[n][16 + u] + bg;
        float go = gl[n][24 + u] + bo;
        float cn = sigmoid_fast(gf) * cr1 + sigmoid_fast(gi) * tanh_fast(gg);
        cr1 = cn;
        h1o = sigmoid_fast(go) * tanh_fast(cn);
    }
}

// stage hv values in LDS, then 128 threads store 16 B each (two 8-B agent stores)
__device__ __forceinline__ void store_h_slot(f16 (*hst)[8], f16* slotbase, int s,
                                             int tid, int n1, int u,
                                             float hv0, float hv1)
{
    hst[n1     ][u] = (f16)hv0;
    hst[n1 + 64][u] = (f16)hv1;
    __syncthreads();
    if (tid < 128) {
        union { v8f16 v; unsigned long long q[2]; } c;
        c.v = *(const v8f16*)&hst[tid][0];
        unsigned long long* gp = (unsigned long long*)(slotbase + ((size_t)tid << 10) + (s << 3));
        __hip_atomic_store(gp,     c.q[0], __ATOMIC_RELAXED, __HIP_MEMORY_SCOPE_AGENT);
        __hip_atomic_store(gp + 1, c.q[1], __ATOMIC_RELAXED, __HIP_MEMORY_SCOPE_AGENT);
    }
}

template<bool XF16>
__global__ void __launch_bounds__(512)
lstm_main(const float* __restrict__ x, const f16* __restrict__ xf,
          const f16* __restrict__ wsW, const float* __restrict__ wsB,
          f16* __restrict__ hseq, const float* __restrict__ c0,
          float* __restrict__ out, unsigned* __restrict__ bar)
{
    __shared__ f16   wlds[32][2056];   // 131584 B
    __shared__ float glds[128][36];    //  18432 B (2-way max conflicts)
    __shared__ f16   hst[128][8];      //   2048 B h-store staging

    const int tid   = threadIdx.x;
    const int wgid  = blockIdx.x;
    const int layer = wgid >> 7;
    const int s     = wgid & 127;
    const int lane  = tid & 63;
    const int wave  = tid >> 6;
    const int quad  = lane >> 4;
    const int l15   = lane & 15;
    const int rb    = wave & 3;        // rows [32rb, 32rb+32)
    const int ks    = wave >> 2;       // K-split (512-half slices per phase)

    for (int idx = tid; idx < 8192; idx += 512) {
        int cc = idx >> 8;
        int k8 = (idx & 255) << 3;
        int col = ((cc >> 3) << 10) + (s << 3) + (cc & 7);
        *(v8f16*)(&wlds[cc][k8]) =
            *(const v8f16*)(wsW + (((size_t)(layer*4096 + col)) << 11) + k8);
    }

    const int u  = tid & 7;
    const int jg = (s << 3) + u;
    const float bi = wsB[layer*4096 +        jg];
    const float bf = wsB[layer*4096 + 1024 + jg];
    const float bg = wsB[layer*4096 + 2048 + jg];
    const float bo = wsB[layer*4096 + 3072 + jg];
    const int n1 = tid >> 3;
    float cr0 = c0[((size_t)layer << 17) + ((size_t)n1 << 10) + jg];
    float cr1 = c0[((size_t)layer << 17) + ((size_t)(n1 + 64) << 10) + jg];

    __syncthreads();

    const int kq   = quad << 3;
    const int row0 = (rb << 5) + l15;
    const int kslc = ks << 9;                       // 512-half K-slice offset
    const int arow = (row0 << 10) + kslc + kq;

    f16* h0b = hseq;
    f16* h1b = hseq + HS_BANK;
    unsigned* cnt0 = bar;            // layer-0 arrivals (monotone, 128/step)
    unsigned* cnt1 = bar + 32;       // layer-1 arrivals

    if (layer == 0) {
        for (int t = 0; t < TSTEPS; ++t) {
            v4f32 acc[2][2] = {};

            // ---- independent phase: x[t] @ Wih (before the flag!) ----
            if (XF16) {
                const f16* p0 = xf + ((size_t)t << 17) + arow;
                kloop16(p0, p0 + (16 << 10), wlds, l15, kq, kslc, acc);
            } else {
                const float* p0 = x + ((size_t)t << 17) + arow;
                const float* p1 = p0 + (16 << 10);
                #pragma unroll
                for (int k = 0; k < 512; k += 32) {
                    v4f32 w0 = *(const v4f32*)(p0 + k), w1 = *(const v4f32*)(p0 + k + 4);
                    v4f32 y0 = *(const v4f32*)(p1 + k), y1 = *(const v4f32*)(p1 + k + 4);
                    v8f16 a0 = cvt8(w0, w1);
                    v8f16 a1 = cvt8(y0, y1);
                    v8f16 b0 = *(const v8f16*)(&wlds[l15     ][kslc + k + kq]);
                    v8f16 b1 = *(const v8f16*)(&wlds[16 + l15][kslc + k + kq]);
                    acc[0][0] = __builtin_amdgcn_mfma_f32_16x16x32_f16(a0, b0, acc[0][0], 0, 0, 0);
                    acc[0][1] = __builtin_amdgcn_mfma_f32_16x16x32_f16(a0, b1, acc[0][1], 0, 0, 0);
                    acc[1][0] = __builtin_amdgcn_mfma_f32_16x16x32_f16(a1, b0, acc[1][0], 0, 0, 0);
                    acc[1][1] = __builtin_amdgcn_mfma_f32_16x16x32_f16(a1, b1, acc[1][1], 0, 0, 0);
                }
            }

            // ---- dependent phase: wait for h[t], then h[t] @ Whh ----
            if (t > 0) {
                if (tid == 0) {
                    unsigned need = (unsigned)(t << 7);
                    while (ld_cnt(cnt0) < need) __builtin_amdgcn_s_sleep(2);
                }
                __syncthreads();
            }
            {
                const f16* p0 = h0b + (size_t)t * SLOT + arow;
                kloop16(p0, p0 + (16 << 10), wlds, l15, kq, 1024 + kslc, acc);
            }

            reduce_splits(acc, glds, rb, quad, l15, ks);

            float hv0, hv1;
            cell2(glds, n1, u, bi, bf, bg, bo, cr0, cr1, hv0, hv1);
            store_h_slot(hst, h0b + (size_t)(t + 1) * SLOT, s, tid, n1, u, hv0, hv1);

            __syncthreads();   // drains the 16-B agent stores (vmcnt) per wave
            if (tid == 0)
                __hip_atomic_fetch_add(cnt0, 1u, __ATOMIC_RELAXED, __HIP_MEMORY_SCOPE_AGENT);
        }
    } else {
        for (int t = 0; t < TSTEPS; ++t) {
            // wait: own recurrence h1[t] (cnt1>=128t) and input h0-out[t] (cnt0>=128(t+1))
            if (tid == 0) {
                unsigned need1 = (unsigned)(t << 7);
                unsigned need0 = (unsigned)((t + 1) << 7);
                while (ld_cnt(cnt1) < need1) __builtin_amdgcn_s_sleep(2);
                while (ld_cnt(cnt0) < need0) __builtin_amdgcn_s_sleep(2);
            }
            __syncthreads();

            v4f32 acc[2][2] = {};
            {
                const f16* p0 = h1b + (size_t)t * SLOT + arow;         // own recurrence
                kloop16(p0, p0 + (16 << 10), wlds, l15, kq, 1024 + kslc, acc);
            }
            {
                const f16* p0 = h0b + (size_t)(t + 1) * SLOT + arow;   // layer-0 output, step t
                kloop16(p0, p0 + (16 << 10), wlds, l15, kq, kslc, acc);
            }

            reduce_splits(acc, glds, rb, quad, l15, ks);

            float hv0, hv1;
            cell2(glds, n1, u, bi, bf, bg, bo, cr0, cr1, hv0, hv1);
            if (t < TSTEPS - 1) {
                store_h_slot(hst, h1b + (size_t)(t + 1) * SLOT, s, tid, n1, u, hv0, hv1);
                __syncthreads();
                if (tid == 0)
                    __hip_atomic_fetch_add(cnt1, 1u, __ATOMIC_RELAXED, __HIP_MEMORY_SCOPE_AGENT);
            } else {
                out[(n1 << 10) + jg] = hv0;
                out[((n1 + 64) << 10) + jg] = hv1;
            }
        }
    }
}

extern "C" void kernel_launch(void* const* d_in, const int* in_sizes, int n_in,
                              void* d_out, int out_size, void* d_ws, size_t ws_size,
                              hipStream_t stream) {
    const float* x   = (const float*)d_in[0];
    const float* h0  = (const float*)d_in[1];
    const float* c0  = (const float*)d_in[2];
    const float* Wih = (const float*)d_in[3];
    const float* Whh = (const float*)d_in[4];
    const float* bih = (const float*)d_in[5];
    const float* bhh = (const float*)d_in[6];
    float* out = (float*)d_out;

    char* ws = (char*)d_ws;
    const bool xf16 = (ws_size >= NEED2);

    f16*      wsW  = (f16*)ws;
    float*    wsB  = (float*)(ws + SZ_W);
    f16*      hseq = (f16*)(ws + SZ_W + SZ_B);
    unsigned* bar  = (unsigned*)(ws + SZ_W + SZ_B + SZ_HSEQ);
    f16*      xf   = (f16*)(ws + NEED1);
    int do_xf = xf16 ? 1 : 0;

    lstm_init<<<2048, 256, 0, stream>>>(x, h0, Wih, Whh, bih, bhh,
                                        wsW, wsB, hseq, bar, xf, do_xf);

    void* kargs[] = { (void*)&x, (void*)&xf, (void*)&wsW, (void*)&wsB,
                      (void*)&hseq, (void*)&c0, (void*)&out, (void*)&bar };
    if (xf16) {
        hipLaunchCooperativeKernel((void*)&lstm_main<true>, dim3(256), dim3(512), kargs, 0, stream);
    } else {
        hipLaunchCooperativeKernel((void*)&lstm_main<false>, dim3(256), dim3(512), kargs, 0, stream);
    }
}